// Round 2
// baseline (447.778 us; speedup 1.0000x reference)
//
#include <hip/hip_runtime.h>

// EdgeLoss: weighted BCE-with-logits mean over 32x1x768x1024 fp32 tensors.
// result = (neg_num * S_pos + pos_num * S_neg) / (pos_num + neg_num) / n
// S_pos = sum over t==1 of bce(x,1), S_neg = sum over t==0 of bce(x,0),
// bce(x,t) = max(x,0) - x*t + log(1+exp(-|x|)).
//
// R1 -> R2: previous version was latency-bound (468 GB/s, VALUBusy 35%,
// VGPR=16: one load pair in flight, divergent branches, ocml log1pf).
// Now: 4x unrolled independent float4 loads (8 KB in flight per wave),
// branchless cndmask selects, __logf(1+e) instead of log1pf. Grid=6144
// chosen so the unrolled body runs exactly once per thread at n=25.17M.

#define WS_POS_CNT 0
#define WS_NEG_CNT 1
#define WS_SUM_POS 2
#define WS_SUM_NEG 3

__device__ __forceinline__ void do_elem(float xv, float tv,
                                        float& cp, float& cn,
                                        float& sp, float& sn) {
  float a = fabsf(xv);
  float e = __expf(-a);                 // v_exp_f32 (w/ pre-scale)
  float l = __logf(1.0f + e);           // v_log_f32 (w/ post-scale)
  float common = fmaxf(xv, 0.f) + l;    // bce(t==0); bce(t==1) = common - x
  bool pos = (tv == 1.0f);
  bool neg = (tv == 0.0f);
  cp += pos ? 1.0f : 0.0f;              // v_cmp + v_cndmask + v_add
  cn += neg ? 1.0f : 0.0f;
  sp += pos ? (common - xv) : 0.0f;
  sn += neg ? common : 0.0f;
}

__device__ __forceinline__ void do_vec4(float4 xv, float4 tv,
                                        float& cp, float& cn,
                                        float& sp, float& sn) {
  do_elem(xv.x, tv.x, cp, cn, sp, sn);
  do_elem(xv.y, tv.y, cp, cn, sp, sn);
  do_elem(xv.z, tv.z, cp, cn, sp, sn);
  do_elem(xv.w, tv.w, cp, cn, sp, sn);
}

__global__ __launch_bounds__(256) void edge_loss_reduce(
    const float* __restrict__ x, const float* __restrict__ t,
    double* __restrict__ ws, long long n) {
  long long tid = (long long)blockIdx.x * blockDim.x + threadIdx.x;
  long long S = (long long)gridDim.x * blockDim.x;
  long long n4 = n >> 2;

  float cp = 0.f, cn = 0.f, sp = 0.f, sn = 0.f;

  const float4* __restrict__ x4 = (const float4*)x;
  const float4* __restrict__ t4 = (const float4*)t;

  long long i = tid;
  // Main unrolled body: 8 independent 16B loads issued before any compute.
  for (; i + 3 * S < n4; i += 4 * S) {
    float4 xa = x4[i];
    float4 xb = x4[i + S];
    float4 xc = x4[i + 2 * S];
    float4 xd = x4[i + 3 * S];
    float4 ta = t4[i];
    float4 tb = t4[i + S];
    float4 tc = t4[i + 2 * S];
    float4 td = t4[i + 3 * S];
    do_vec4(xa, ta, cp, cn, sp, sn);
    do_vec4(xb, tb, cp, cn, sp, sn);
    do_vec4(xc, tc, cp, cn, sp, sn);
    do_vec4(xd, td, cp, cn, sp, sn);
  }
  // float4 remainder
  for (; i < n4; i += S) {
    do_vec4(x4[i], t4[i], cp, cn, sp, sn);
  }
  // scalar tail (n not multiple of 4)
  for (long long j = (n4 << 2) + tid; j < n; j += S) {
    do_elem(x[j], t[j], cp, cn, sp, sn);
  }

  // wave-64 shuffle reduction
  #pragma unroll
  for (int off = 32; off > 0; off >>= 1) {
    cp += __shfl_down(cp, off, 64);
    cn += __shfl_down(cn, off, 64);
    sp += __shfl_down(sp, off, 64);
    sn += __shfl_down(sn, off, 64);
  }

  __shared__ float s_cp[4], s_cn[4], s_sp[4], s_sn[4];
  int lane = threadIdx.x & 63;
  int wave = threadIdx.x >> 6;
  if (lane == 0) { s_cp[wave] = cp; s_cn[wave] = cn; s_sp[wave] = sp; s_sn[wave] = sn; }
  __syncthreads();
  if (threadIdx.x == 0) {
    float tcp = 0.f, tcn = 0.f, tsp = 0.f, tsn = 0.f;
    #pragma unroll
    for (int k = 0; k < 4; ++k) { tcp += s_cp[k]; tcn += s_cn[k]; tsp += s_sp[k]; tsn += s_sn[k]; }
    atomicAdd(&ws[WS_POS_CNT], (double)tcp);
    atomicAdd(&ws[WS_NEG_CNT], (double)tcn);
    atomicAdd(&ws[WS_SUM_POS], (double)tsp);
    atomicAdd(&ws[WS_SUM_NEG], (double)tsn);
  }
}

__global__ void edge_loss_finalize(const double* __restrict__ ws,
                                   float* __restrict__ out, double inv_n) {
  double pos = ws[WS_POS_CNT];
  double neg = ws[WS_NEG_CNT];
  double s = pos + neg;
  double res = (neg * ws[WS_SUM_POS] + pos * ws[WS_SUM_NEG]) / s * inv_n;
  out[0] = (float)res;
}

extern "C" void kernel_launch(void* const* d_in, const int* in_sizes, int n_in,
                              void* d_out, int out_size, void* d_ws, size_t ws_size,
                              hipStream_t stream) {
  const float* x = (const float*)d_in[0];
  const float* t = (const float*)d_in[1];
  long long n = (long long)in_sizes[0];
  double* ws = (double*)d_ws;

  hipMemsetAsync(ws, 0, 4 * sizeof(double), stream);

  const int block = 256;
  // 6144 blocks * 256 threads * 4 float4 = 25,165,824 elements: at the bench
  // shape the unrolled body executes exactly once per thread (no loop).
  const int grid = 6144;
  edge_loss_reduce<<<grid, block, 0, stream>>>(x, t, ws, n);
  edge_loss_finalize<<<1, 1, 0, stream>>>(ws, (float*)d_out, 1.0 / (double)n);
}

// Round 3
// 219.689 us; speedup vs baseline: 2.0382x; 2.0382x over previous
//
#include <hip/hip_runtime.h>

// EdgeLoss: weighted BCE-with-logits mean over 32x1x768x1024 fp32 tensors.
// result = (neg_num * S_pos + pos_num * S_neg) / (pos_num + neg_num) / n
// S_pos = sum over t==1 of bce(x,1), S_neg = sum over t==0 of bce(x,0),
// bce(x,t) = max(x,0) - x*t + log(1+exp(-|x|)).
//
// R2 -> R3: R1/R2 were dominated by the contended fp64 atomicAdd tail
// (CAS-loop on 4 shared doubles; 16k/24k serialized RMWs ~= 200/300 us,
// matching both measurements). Replaced with a deterministic two-stage
// reduction: stage 1 writes per-block partials (plain stores), stage 2
// (one block) reduces 6144x4 floats in double precision. No atomics.

#define GRID1 6144
#define BLOCK 256

__device__ __forceinline__ void do_elem(float xv, float tv,
                                        float& cp, float& cn,
                                        float& sp, float& sn) {
  float a = fabsf(xv);
  float e = __expf(-a);                 // v_exp_f32
  float l = __logf(1.0f + e);           // v_log_f32
  float common = fmaxf(xv, 0.f) + l;    // bce(t==0); bce(t==1) = common - x
  bool pos = (tv == 1.0f);
  bool neg = (tv == 0.0f);
  cp += pos ? 1.0f : 0.0f;
  cn += neg ? 1.0f : 0.0f;
  sp += pos ? (common - xv) : 0.0f;
  sn += neg ? common : 0.0f;
}

__device__ __forceinline__ void do_vec4(float4 xv, float4 tv,
                                        float& cp, float& cn,
                                        float& sp, float& sn) {
  do_elem(xv.x, tv.x, cp, cn, sp, sn);
  do_elem(xv.y, tv.y, cp, cn, sp, sn);
  do_elem(xv.z, tv.z, cp, cn, sp, sn);
  do_elem(xv.w, tv.w, cp, cn, sp, sn);
}

__global__ __launch_bounds__(BLOCK) void edge_loss_stage1(
    const float* __restrict__ x, const float* __restrict__ t,
    float* __restrict__ partials, long long n) {
  long long tid = (long long)blockIdx.x * BLOCK + threadIdx.x;
  long long S = (long long)gridDim.x * BLOCK;
  long long n4 = n >> 2;

  float cp = 0.f, cn = 0.f, sp = 0.f, sn = 0.f;

  const float4* __restrict__ x4 = (const float4*)x;
  const float4* __restrict__ t4 = (const float4*)t;

  long long i = tid;
  // 8 independent 16B loads in flight before any compute.
  for (; i + 3 * S < n4; i += 4 * S) {
    float4 xa = x4[i];
    float4 xb = x4[i + S];
    float4 xc = x4[i + 2 * S];
    float4 xd = x4[i + 3 * S];
    float4 ta = t4[i];
    float4 tb = t4[i + S];
    float4 tc = t4[i + 2 * S];
    float4 td = t4[i + 3 * S];
    do_vec4(xa, ta, cp, cn, sp, sn);
    do_vec4(xb, tb, cp, cn, sp, sn);
    do_vec4(xc, tc, cp, cn, sp, sn);
    do_vec4(xd, td, cp, cn, sp, sn);
  }
  for (; i < n4; i += S) {
    do_vec4(x4[i], t4[i], cp, cn, sp, sn);
  }
  for (long long j = (n4 << 2) + tid; j < n; j += S) {
    do_elem(x[j], t[j], cp, cn, sp, sn);
  }

  // wave-64 shuffle reduction
  #pragma unroll
  for (int off = 32; off > 0; off >>= 1) {
    cp += __shfl_down(cp, off, 64);
    cn += __shfl_down(cn, off, 64);
    sp += __shfl_down(sp, off, 64);
    sn += __shfl_down(sn, off, 64);
  }

  __shared__ float s_cp[4], s_cn[4], s_sp[4], s_sn[4];
  int lane = threadIdx.x & 63;
  int wave = threadIdx.x >> 6;
  if (lane == 0) { s_cp[wave] = cp; s_cn[wave] = cn; s_sp[wave] = sp; s_sn[wave] = sn; }
  __syncthreads();
  if (threadIdx.x == 0) {
    float tcp = 0.f, tcn = 0.f, tsp = 0.f, tsn = 0.f;
    #pragma unroll
    for (int k = 0; k < 4; ++k) { tcp += s_cp[k]; tcn += s_cn[k]; tsp += s_sp[k]; tsn += s_sn[k]; }
    int G = gridDim.x;
    partials[0 * G + blockIdx.x] = tcp;   // pos count
    partials[1 * G + blockIdx.x] = tcn;   // neg count
    partials[2 * G + blockIdx.x] = tsp;   // sum_pos
    partials[3 * G + blockIdx.x] = tsn;   // sum_neg
  }
}

__global__ __launch_bounds__(BLOCK) void edge_loss_stage2(
    const float* __restrict__ partials, float* __restrict__ out,
    int G, double inv_n) {
  double acc[4] = {0.0, 0.0, 0.0, 0.0};
  for (int i = threadIdx.x; i < G; i += BLOCK) {
    #pragma unroll
    for (int c = 0; c < 4; ++c) acc[c] += (double)partials[c * G + i];
  }
  // wave-64 shuffle reduction on doubles
  #pragma unroll
  for (int off = 32; off > 0; off >>= 1) {
    #pragma unroll
    for (int c = 0; c < 4; ++c) acc[c] += __shfl_down(acc[c], off, 64);
  }
  __shared__ double s_acc[4][4];
  int lane = threadIdx.x & 63;
  int wave = threadIdx.x >> 6;
  if (lane == 0) {
    #pragma unroll
    for (int c = 0; c < 4; ++c) s_acc[wave][c] = acc[c];
  }
  __syncthreads();
  if (threadIdx.x == 0) {
    double pos = 0, neg = 0, spos = 0, sneg = 0;
    #pragma unroll
    for (int w = 0; w < 4; ++w) {
      pos += s_acc[w][0]; neg += s_acc[w][1];
      spos += s_acc[w][2]; sneg += s_acc[w][3];
    }
    double s = pos + neg;
    out[0] = (float)((neg * spos + pos * sneg) / s * inv_n);
  }
}

extern "C" void kernel_launch(void* const* d_in, const int* in_sizes, int n_in,
                              void* d_out, int out_size, void* d_ws, size_t ws_size,
                              hipStream_t stream) {
  const float* x = (const float*)d_in[0];
  const float* t = (const float*)d_in[1];
  long long n = (long long)in_sizes[0];
  float* partials = (float*)d_ws;  // 4 * GRID1 floats = 96 KB, all written

  edge_loss_stage1<<<GRID1, BLOCK, 0, stream>>>(x, t, partials, n);
  edge_loss_stage2<<<1, BLOCK, 0, stream>>>(partials, (float*)d_out,
                                            GRID1, 1.0 / (double)n);
}

// Round 4
// 215.018 us; speedup vs baseline: 2.0825x; 1.0217x over previous
//
#include <hip/hip_runtime.h>

// EdgeLoss: weighted BCE-with-logits mean over 32x1x768x1024 fp32 tensors.
// result = (neg_num * S_pos + pos_num * S_neg) / (pos_num + neg_num) / n
// S_pos = sum over t==1 of bce(x,1), S_neg = sum over t==0 of bce(x,0),
// bce(x,t) = max(x,0) - x*t + log(1+exp(-|x|))  (= softplus for t=0).
//
// R3 -> R4: R3's stage1 (75 us, 2.66 TB/s effective) was latency-bound:
// VGPR=24 proves the compiler serialized the "8 independent loads", and the
// one-shot structure left the memory pipe idle during each wave's entire
// compute+reduce phase (3 dispatch rounds of 8 blocks/CU).
// Now: resident grid (2048 blocks = 8 blocks/CU, single round), per-thread
// streaming loop over 12 float4 pairs with depth-1 register prefetch so
// every wave keeps ~2 KB outstanding while computing. launch_bounds(256,8)
// guarantees 32 waves/CU.

#define GRID1 2048
#define BLOCK 256

__device__ __forceinline__ void do_elem(float xv, float tv,
                                        float& cp, float& cn,
                                        float& sp, float& sn) {
  float a = fabsf(xv);
  float e = __expf(-a);                 // v_exp_f32
  float l = __logf(1.0f + e);           // v_log_f32
  float c = fmaxf(xv, 0.f) + l;         // softplus(x) = bce(t==0); bce(t==1)=c-x
  bool pos = (tv == 1.0f);
  bool neg = (tv == 0.0f);
  cp += pos ? 1.0f : 0.0f;
  cn += neg ? 1.0f : 0.0f;
  sp += pos ? (c - xv) : 0.0f;
  sn += neg ? c : 0.0f;
}

__device__ __forceinline__ void do_vec4(float4 xv, float4 tv,
                                        float& cp, float& cn,
                                        float& sp, float& sn) {
  do_elem(xv.x, tv.x, cp, cn, sp, sn);
  do_elem(xv.y, tv.y, cp, cn, sp, sn);
  do_elem(xv.z, tv.z, cp, cn, sp, sn);
  do_elem(xv.w, tv.w, cp, cn, sp, sn);
}

__global__ __launch_bounds__(BLOCK, 8) void edge_loss_stage1(
    const float* __restrict__ x, const float* __restrict__ t,
    float* __restrict__ partials, long long n) {
  long long tid = (long long)blockIdx.x * BLOCK + threadIdx.x;
  long long S = (long long)gridDim.x * BLOCK;
  long long n4 = n >> 2;

  float cp = 0.f, cn = 0.f, sp = 0.f, sn = 0.f;

  const float4* __restrict__ x4 = (const float4*)x;
  const float4* __restrict__ t4 = (const float4*)t;

  // Depth-1 software pipeline: next iteration's loads are in flight while
  // the current pair is being processed.
  long long i = tid;
  if (i < n4) {
    float4 xa = x4[i];
    float4 ta = t4[i];
    long long nxt = i + S;
    while (nxt < n4) {
      float4 xb = x4[nxt];            // issued before compute below
      float4 tb = t4[nxt];
      do_vec4(xa, ta, cp, cn, sp, sn);
      xa = xb;
      ta = tb;
      nxt += S;
    }
    do_vec4(xa, ta, cp, cn, sp, sn);
  }
  // scalar tail (n not a multiple of 4)
  for (long long j = (n4 << 2) + tid; j < n; j += S) {
    do_elem(x[j], t[j], cp, cn, sp, sn);
  }

  // wave-64 shuffle reduction
  #pragma unroll
  for (int off = 32; off > 0; off >>= 1) {
    cp += __shfl_down(cp, off, 64);
    cn += __shfl_down(cn, off, 64);
    sp += __shfl_down(sp, off, 64);
    sn += __shfl_down(sn, off, 64);
  }

  __shared__ float s_cp[4], s_cn[4], s_sp[4], s_sn[4];
  int lane = threadIdx.x & 63;
  int wave = threadIdx.x >> 6;
  if (lane == 0) { s_cp[wave] = cp; s_cn[wave] = cn; s_sp[wave] = sp; s_sn[wave] = sn; }
  __syncthreads();
  if (threadIdx.x == 0) {
    float tcp = 0.f, tcn = 0.f, tsp = 0.f, tsn = 0.f;
    #pragma unroll
    for (int k = 0; k < 4; ++k) { tcp += s_cp[k]; tcn += s_cn[k]; tsp += s_sp[k]; tsn += s_sn[k]; }
    int G = gridDim.x;
    partials[0 * G + blockIdx.x] = tcp;   // pos count
    partials[1 * G + blockIdx.x] = tcn;   // neg count
    partials[2 * G + blockIdx.x] = tsp;   // sum_pos
    partials[3 * G + blockIdx.x] = tsn;   // sum_neg
  }
}

__global__ __launch_bounds__(BLOCK) void edge_loss_stage2(
    const float* __restrict__ partials, float* __restrict__ out,
    int G, double inv_n) {
  double acc[4] = {0.0, 0.0, 0.0, 0.0};
  for (int i = threadIdx.x; i < G; i += BLOCK) {
    #pragma unroll
    for (int c = 0; c < 4; ++c) acc[c] += (double)partials[c * G + i];
  }
  #pragma unroll
  for (int off = 32; off > 0; off >>= 1) {
    #pragma unroll
    for (int c = 0; c < 4; ++c) acc[c] += __shfl_down(acc[c], off, 64);
  }
  __shared__ double s_acc[4][4];
  int lane = threadIdx.x & 63;
  int wave = threadIdx.x >> 6;
  if (lane == 0) {
    #pragma unroll
    for (int c = 0; c < 4; ++c) s_acc[wave][c] = acc[c];
  }
  __syncthreads();
  if (threadIdx.x == 0) {
    double pos = 0, neg = 0, spos = 0, sneg = 0;
    #pragma unroll
    for (int w = 0; w < 4; ++w) {
      pos += s_acc[w][0]; neg += s_acc[w][1];
      spos += s_acc[w][2]; sneg += s_acc[w][3];
    }
    double s = pos + neg;
    out[0] = (float)((neg * spos + pos * sneg) / s * inv_n);
  }
}

extern "C" void kernel_launch(void* const* d_in, const int* in_sizes, int n_in,
                              void* d_out, int out_size, void* d_ws, size_t ws_size,
                              hipStream_t stream) {
  const float* x = (const float*)d_in[0];
  const float* t = (const float*)d_in[1];
  long long n = (long long)in_sizes[0];
  float* partials = (float*)d_ws;  // 4 * GRID1 floats = 32 KB, fully written

  edge_loss_stage1<<<GRID1, BLOCK, 0, stream>>>(x, t, partials, n);
  edge_loss_stage2<<<1, BLOCK, 0, stream>>>(partials, (float*)d_out,
                                            GRID1, 1.0 / (double)n);
}